// Round 1
// baseline (1361.461 us; speedup 1.0000x reference)
//
#include <hip/hip_runtime.h>
#include <cstdint>
#include <cstddef>

#define HH 256
#define WW 256
#define HWW (HH * WW)

// Generic direct 3x3 conv, stride 1, pad 1, NCHW fp32.
// CIN is 16 or 32 (32 == concat of two 16-ch tensors inA,inB).
// ACT: 0 none, 1 relu, 2 sigmoid.
// TILE x TILE output pixels per block (256 threads), PPT x PPT pixels/thread.
// FUSE (requires COUT==1): out[c] = gsrc[c] * sigmoid(conv) for c in 0..15.
template <int CIN, int COUT, int ACT, int TILE, int PPT, bool FUSE>
__global__ __launch_bounds__(256) void conv3x3_k(
    const float* __restrict__ inA, const float* __restrict__ inB,
    const float* __restrict__ wgt, const float* __restrict__ bias,
    const float* __restrict__ gsrc, float* __restrict__ out) {
  constexpr int PT = TILE + 2;
  constexpr int CHUNK = 8;
  constexpr int TXT = TILE / PPT;  // threads per row; TXT*TXT must be 256
  __shared__ float s_in[CHUNK][PT * PT];
  __shared__ float s_w[COUT * CIN * 12];

  const int b = blockIdx.z;
  const int ty0 = blockIdx.y * TILE;
  const int tx0 = blockIdx.x * TILE;
  const int tid = threadIdx.x;

  // Stage weights (OIHW), padded to 12 floats per (o,c) so float4 reads align.
  for (int i = tid; i < COUT * CIN * 9; i += 256) {
    int k = i % 9;
    int oc = i / 9;
    s_w[oc * 12 + k] = wgt[i];
  }

  float acc[COUT][PPT * PPT];
#pragma unroll
  for (int o = 0; o < COUT; ++o) {
    float bv = bias[o];
#pragma unroll
    for (int p = 0; p < PPT * PPT; ++p) acc[o][p] = bv;
  }

  const int thy = (tid / TXT) * PPT;
  const int thx = (tid % TXT) * PPT;

  for (int c0 = 0; c0 < CIN; c0 += CHUNK) {
    __syncthreads();
    // Stage CHUNK channels of the padded input tile (zero padding).
    for (int i = tid; i < CHUNK * PT * PT; i += 256) {
      int cc = i / (PT * PT);
      int pos = i - cc * (PT * PT);
      int iy = pos / PT;
      int ix = pos - iy * PT;
      int gy = ty0 + iy - 1;
      int gx = tx0 + ix - 1;
      int c = c0 + cc;
      const float* src = inA;
      int cl = c;
      if (CIN == 32 && c >= 16) { src = inB; cl = c - 16; }
      float v = 0.f;
      if (gy >= 0 && gy < HH && gx >= 0 && gx < WW)
        v = src[((size_t)b * 16 + cl) * HWW + gy * WW + gx];
      s_in[cc][pos] = v;
    }
    __syncthreads();

#pragma unroll
    for (int cc = 0; cc < CHUNK; ++cc) {
      const int c = c0 + cc;
      float win[PPT + 2][PPT + 2];
#pragma unroll
      for (int wy = 0; wy < PPT + 2; ++wy)
#pragma unroll
        for (int wx = 0; wx < PPT + 2; ++wx)
          win[wy][wx] = s_in[cc][(thy + wy) * PT + thx + wx];
#pragma unroll
      for (int o = 0; o < COUT; ++o) {
        const float4 w0 = *reinterpret_cast<const float4*>(&s_w[(o * CIN + c) * 12]);
        const float4 w1 = *reinterpret_cast<const float4*>(&s_w[(o * CIN + c) * 12 + 4]);
        const float w8 = s_w[(o * CIN + c) * 12 + 8];
#pragma unroll
        for (int py = 0; py < PPT; ++py)
#pragma unroll
          for (int px = 0; px < PPT; ++px) {
            float s = fmaf(win[py][px], w0.x,
                      fmaf(win[py][px + 1], w0.y,
                      fmaf(win[py][px + 2], w0.z,
                      fmaf(win[py + 1][px], w0.w,
                      fmaf(win[py + 1][px + 1], w1.x,
                      fmaf(win[py + 1][px + 2], w1.y,
                      fmaf(win[py + 2][px], w1.z,
                      fmaf(win[py + 2][px + 1], w1.w,
                           win[py + 2][px + 2] * w8))))))));
            acc[o][py * PPT + px] += s;
          }
      }
    }
  }

#pragma unroll
  for (int py = 0; py < PPT; ++py)
#pragma unroll
    for (int px = 0; px < PPT; ++px) {
      const int oy = ty0 + thy + py;
      const int ox = tx0 + thx + px;
      if constexpr (FUSE) {
        float m = 1.0f / (1.0f + expf(-acc[0][py * PPT + px]));
#pragma unroll
        for (int c = 0; c < 16; ++c) {
          size_t idx = ((size_t)b * 16 + c) * HWW + (size_t)oy * WW + ox;
          out[idx] = gsrc[idx] * m;
        }
      } else {
#pragma unroll
        for (int o = 0; o < COUT; ++o) {
          float v = acc[o][py * PPT + px];
          if (ACT == 1) v = fmaxf(v, 0.f);
          if (ACT == 2) v = 1.0f / (1.0f + expf(-v));
          out[((size_t)b * COUT + o) * HWW + (size_t)oy * WW + ox] = v;
        }
      }
    }
}

// Modulated deformable conv 3x3 (torchvision semantics), 16->16, + ReLU.
// om: [B,27,H,W] raw (18 offsets interleaved y,x; 9 mask logits).
__global__ __launch_bounds__(256) void deform_k(
    const float* __restrict__ x, const float* __restrict__ om,
    const float* __restrict__ wgt, const float* __restrict__ bias,
    float* __restrict__ out) {
  __shared__ float s_w[9][16][16];  // [k][c][o]
  const int tid = threadIdx.x;
  for (int i = tid; i < 2304; i += 256) {
    int k = i % 9;
    int oc = i / 9;  // o*16 + c
    int o = oc / 16;
    int c = oc - o * 16;
    s_w[k][c][o] = wgt[i];
  }
  __syncthreads();

  const int b = blockIdx.z;
  const int pixel = blockIdx.x * 256 + tid;
  const int y = pixel >> 8;
  const int xq = pixel & 255;
  const float* xb = x + (size_t)b * 16 * HWW;
  const float* omb = om + (size_t)b * 27 * HWW;

  float acc[16];
#pragma unroll
  for (int o = 0; o < 16; ++o) acc[o] = bias[o];

  for (int k = 0; k < 9; ++k) {
    float offy = omb[(size_t)(2 * k) * HWW + pixel];
    float offx = omb[(size_t)(2 * k + 1) * HWW + pixel];
    float mr = omb[(size_t)(18 + k) * HWW + pixel];
    float m = 1.0f / (1.0f + expf(-mr));
    float py = (float)y + (float)(k / 3 - 1) + offy;
    float px = (float)xq + (float)(k % 3 - 1) + offx;
    float y0f = floorf(py);
    float x0f = floorf(px);
    float dy = py - y0f;
    float dx = px - x0f;
    int y0 = (int)y0f;
    int x0 = (int)x0f;
    int y1 = y0 + 1;
    int x1 = x0 + 1;
    bool vy0 = (y0 >= 0) && (y0 < HH);
    bool vy1 = (y1 >= 0) && (y1 < HH);
    bool vx0 = (x0 >= 0) && (x0 < WW);
    bool vx1 = (x1 >= 0) && (x1 < WW);
    int yc0 = min(max(y0, 0), HH - 1);
    int yc1 = min(max(y1, 0), HH - 1);
    int xc0 = min(max(x0, 0), WW - 1);
    int xc1 = min(max(x1, 0), WW - 1);
    float w00 = (1.f - dy) * (1.f - dx) * m;
    float w01 = (1.f - dy) * dx * m;
    float w10 = dy * (1.f - dx) * m;
    float w11 = dy * dx * m;
    if (!(vy0 && vx0)) w00 = 0.f;
    if (!(vy0 && vx1)) w01 = 0.f;
    if (!(vy1 && vx0)) w10 = 0.f;
    if (!(vy1 && vx1)) w11 = 0.f;
    int i00 = yc0 * WW + xc0;
    int i01 = yc0 * WW + xc1;
    int i10 = yc1 * WW + xc0;
    int i11 = yc1 * WW + xc1;
#pragma unroll
    for (int c = 0; c < 16; ++c) {
      const float* xc = xb + (size_t)c * HWW;
      float s = xc[i00] * w00 + xc[i01] * w01 + xc[i10] * w10 + xc[i11] * w11;
      const float4* wrow = reinterpret_cast<const float4*>(&s_w[k][c][0]);
      float4 wa = wrow[0], wbv = wrow[1], wcv = wrow[2], wdv = wrow[3];
      acc[0]  = fmaf(s, wa.x, acc[0]);
      acc[1]  = fmaf(s, wa.y, acc[1]);
      acc[2]  = fmaf(s, wa.z, acc[2]);
      acc[3]  = fmaf(s, wa.w, acc[3]);
      acc[4]  = fmaf(s, wbv.x, acc[4]);
      acc[5]  = fmaf(s, wbv.y, acc[5]);
      acc[6]  = fmaf(s, wbv.z, acc[6]);
      acc[7]  = fmaf(s, wbv.w, acc[7]);
      acc[8]  = fmaf(s, wcv.x, acc[8]);
      acc[9]  = fmaf(s, wcv.y, acc[9]);
      acc[10] = fmaf(s, wcv.z, acc[10]);
      acc[11] = fmaf(s, wcv.w, acc[11]);
      acc[12] = fmaf(s, wdv.x, acc[12]);
      acc[13] = fmaf(s, wdv.y, acc[13]);
      acc[14] = fmaf(s, wdv.z, acc[14]);
      acc[15] = fmaf(s, wdv.w, acc[15]);
    }
  }
#pragma unroll
  for (int o = 0; o < 16; ++o)
    out[((size_t)b * 16 + o) * HWW + pixel] = fmaxf(acc[o], 0.f);
}

extern "C" void kernel_launch(void* const* d_in, const int* in_sizes, int n_in,
                              void* d_out, int out_size, void* d_ws, size_t ws_size,
                              hipStream_t stream) {
  (void)in_sizes; (void)n_in; (void)out_size; (void)ws_size;
  const float* f_E = (const float*)d_in[0];
  const float* f_F = (const float*)d_in[1];
  const float* att_w1 = (const float*)d_in[2];
  const float* att_b1 = (const float*)d_in[3];
  const float* att_w2 = (const float*)d_in[4];
  const float* att_b2 = (const float*)d_in[5];
  const float* ref_w = (const float*)d_in[6];
  const float* ref_b = (const float*)d_in[7];
  const float* om_w1 = (const float*)d_in[8];
  const float* om_b1 = (const float*)d_in[9];
  const float* om_w2 = (const float*)d_in[10];
  const float* om_b2 = (const float*)d_in[11];
  const float* om_w3 = (const float*)d_in[12];
  const float* om_b3 = (const float*)d_in[13];
  const float* dcb_w = (const float*)d_in[14];
  const float* dcb_b = (const float*)d_in[15];
  const float* dcbref_w = (const float*)d_in[16];
  const float* dcbref_b = (const float*)d_in[17];
  const float* fin_w = (const float*)d_in[18];
  const float* fin_b = (const float*)d_in[19];
  float* outp = (float*)d_out;

  const size_t T16 = (size_t)4 * 16 * HWW;  // one 16-ch fp32 tensor
  float* R0 = (float*)d_ws;     // conv_a, later om_t3
  float* R1 = R0 + T16;         // f_Esa, later f_Edc
  float* R2 = R1 + T16;         // f_EFsa
  float* R3 = R2 + T16;         // om_t2, later f_EFdc
  float* R4 = R3 + T16;         // om (27 ch)

  dim3 blk(256);
  dim3 g32(WW / 32, HH / 32, 4);
  dim3 g16(WW / 16, HH / 16, 4);

  // K1: conv_a = relu(conv(cat(f_E,f_F), att_w1))
  conv3x3_k<32, 16, 1, 32, 2, false><<<g32, blk, 0, stream>>>(f_E, f_F, att_w1, att_b1, nullptr, R0);
  // K2: f_Esa = f_E * sigmoid(conv(conv_a, att_w2))
  conv3x3_k<16, 1, 2, 32, 2, true><<<g32, blk, 0, stream>>>(R0, nullptr, att_w2, att_b2, f_E, R1);
  // K3: f_EFsa = relu(conv(cat(f_Esa,f_F), ref_w))
  conv3x3_k<32, 16, 1, 32, 2, false><<<g32, blk, 0, stream>>>(R1, f_F, ref_w, ref_b, nullptr, R2);
  // K4: om_t2 = relu(conv(cat(f_E,f_F), om_w1))
  conv3x3_k<32, 16, 1, 32, 2, false><<<g32, blk, 0, stream>>>(f_E, f_F, om_w1, om_b1, nullptr, R3);
  // K5: om_t3 = relu(conv(om_t2, om_w2))
  conv3x3_k<16, 16, 1, 32, 2, false><<<g32, blk, 0, stream>>>(R3, nullptr, om_w2, om_b2, nullptr, R0);
  // K6: om = conv(om_t3, om_w3)   (raw; 27 ch)
  conv3x3_k<16, 27, 0, 16, 1, false><<<g16, blk, 0, stream>>>(R0, nullptr, om_w3, om_b3, nullptr, R4);
  // K7: f_Edc = relu(deform_conv(f_E, om, dcb_w))
  deform_k<<<dim3(HWW / 256, 1, 4), blk, 0, stream>>>(f_E, R4, dcb_w, dcb_b, R1);
  // K8: f_EFdc = relu(conv(cat(f_Edc,f_F), dcbref_w))
  conv3x3_k<32, 16, 1, 32, 2, false><<<g32, blk, 0, stream>>>(R1, f_F, dcbref_w, dcbref_b, nullptr, R3);
  // K9: out = relu(conv(cat(f_EFsa,f_EFdc), fin_w))
  conv3x3_k<32, 16, 1, 32, 2, false><<<g32, blk, 0, stream>>>(R2, R3, fin_w, fin_b, nullptr, outp);
}

// Round 2
// 460.220 us; speedup vs baseline: 2.9583x; 2.9583x over previous
//
#include <hip/hip_runtime.h>
#include <cstdint>
#include <cstddef>

#define HH 256
#define WW 256
#define HWW (HH * WW)

// ---------------------------------------------------------------------------
// Weight repack: OIHW -> [cin][9][cout] so conv inner loops read weights at
// wave-uniform addresses (compiler emits s_load; FMA uses free SGPR operand).
// ---------------------------------------------------------------------------
struct RepackDesc { const float* src; float* dst; int cin; int cout; };
struct RepackArgs { RepackDesc d[9]; };

__global__ __launch_bounds__(256) void repack_k(RepackArgs a) {
  const RepackDesc t = a.d[blockIdx.x];
  const int n = t.cin * t.cout * 9;
  for (int i = threadIdx.x; i < n; i += 256) {
    int k = i % 9;
    int rest = i / 9;
    int c = rest % t.cin;
    int o = rest / t.cin;
    t.dst[(c * 9 + k) * t.cout + o] = t.src[(o * t.cin + c) * 9 + k];
  }
}

// ---------------------------------------------------------------------------
// Direct 3x3 conv, stride 1, pad 1, NCHW fp32. 1 output pixel per thread.
// Tile: 32 (x) by 8 (y), 256 threads, grid 8 x 32 x B = 1024 blocks.
// CIN 16 or 32 (32 == concat(inA,inB)). Weights pre-repacked [cin][9][cout].
// ACT: 0 none, 1 relu. FUSE (COUT==1): out[c] = gsrc[c] * sigmoid(conv).
// ---------------------------------------------------------------------------
template <int CIN, int COUT, int ACT, bool FUSE>
__global__ __launch_bounds__(256) void conv_v2(
    const float* __restrict__ inA, const float* __restrict__ inB,
    const float* __restrict__ wt, const float* __restrict__ bias,
    const float* __restrict__ gsrc, float* __restrict__ out) {
  constexpr int TX = 32, TY = 8;
  constexpr int PX = TX + 2, PY = TY + 2;      // 34 x 10 padded tile
  constexpr int CHUNK = 8;
  __shared__ float s_in[CHUNK][PY * PX];

  const int b = blockIdx.z;
  const int tx0 = blockIdx.x * TX;
  const int ty0 = blockIdx.y * TY;
  const int tid = threadIdx.x;
  const int thx = tid & 31;
  const int thy = tid >> 5;

  float acc[COUT];
#pragma unroll
  for (int o = 0; o < COUT; ++o) acc[o] = bias[o];

  for (int c0 = 0; c0 < CIN; c0 += CHUNK) {
    __syncthreads();
    for (int i = tid; i < CHUNK * PY * PX; i += 256) {
      int cc = i / (PY * PX);
      int pos = i - cc * (PY * PX);
      int iy = pos / PX;
      int ix = pos - iy * PX;
      int gy = ty0 + iy - 1;
      int gx = tx0 + ix - 1;
      int c = c0 + cc;
      const float* src = inA;
      int cl = c;
      if (CIN == 32 && c >= 16) { src = inB; cl = c - 16; }
      float v = 0.f;
      if (gy >= 0 && gy < HH && gx >= 0 && gx < WW)
        v = src[((size_t)b * 16 + cl) * HWW + gy * WW + gx];
      s_in[cc][pos] = v;
    }
    __syncthreads();

#pragma unroll
    for (int cc = 0; cc < CHUNK; ++cc) {
      float win[9];
#pragma unroll
      for (int wy = 0; wy < 3; ++wy)
#pragma unroll
        for (int wx = 0; wx < 3; ++wx)
          win[wy * 3 + wx] = s_in[cc][(thy + wy) * PX + thx + wx];
      const float* wc = wt + (size_t)(c0 + cc) * 9 * COUT;  // uniform
#pragma unroll
      for (int k = 0; k < 9; ++k) {
        const float wv = win[k];
#pragma unroll
        for (int o = 0; o < COUT; ++o)
          acc[o] = fmaf(wv, wc[k * COUT + o], acc[o]);
      }
    }
  }

  const int oy = ty0 + thy;
  const int ox = tx0 + thx;
  if constexpr (FUSE) {
    float m = 1.0f / (1.0f + expf(-acc[0]));
#pragma unroll
    for (int c = 0; c < 16; ++c) {
      size_t idx = ((size_t)b * 16 + c) * HWW + (size_t)oy * WW + ox;
      out[idx] = gsrc[idx] * m;
    }
  } else {
#pragma unroll
    for (int o = 0; o < COUT; ++o) {
      float v = acc[o];
      if (ACT == 1) v = fmaxf(v, 0.f);
      out[((size_t)b * COUT + o) * HWW + (size_t)oy * WW + ox] = v;
    }
  }
}

// ---------------------------------------------------------------------------
// Modulated deformable conv 3x3 (torchvision semantics), 16->16, + ReLU.
// Weights pre-repacked [c][9][o] -> uniform scalar loads, no LDS.
// ---------------------------------------------------------------------------
__global__ __launch_bounds__(256) void deform_v2(
    const float* __restrict__ x, const float* __restrict__ om,
    const float* __restrict__ wt, const float* __restrict__ bias,
    float* __restrict__ out) {
  const int b = blockIdx.z;
  const int pixel = blockIdx.x * 256 + threadIdx.x;
  const int y = pixel >> 8;
  const int xq = pixel & 255;
  const float* xb = x + (size_t)b * 16 * HWW;
  const float* omb = om + (size_t)b * 27 * HWW;

  float acc[16];
#pragma unroll
  for (int o = 0; o < 16; ++o) acc[o] = bias[o];

#pragma unroll
  for (int k = 0; k < 9; ++k) {
    float offy = omb[(size_t)(2 * k) * HWW + pixel];
    float offx = omb[(size_t)(2 * k + 1) * HWW + pixel];
    float mr = omb[(size_t)(18 + k) * HWW + pixel];
    float m = 1.0f / (1.0f + expf(-mr));
    float py = (float)y + (float)(k / 3 - 1) + offy;
    float px = (float)xq + (float)(k % 3 - 1) + offx;
    float y0f = floorf(py);
    float x0f = floorf(px);
    float dy = py - y0f;
    float dx = px - x0f;
    int y0 = (int)y0f;
    int x0 = (int)x0f;
    int y1 = y0 + 1;
    int x1 = x0 + 1;
    bool vy0 = (y0 >= 0) && (y0 < HH);
    bool vy1 = (y1 >= 0) && (y1 < HH);
    bool vx0 = (x0 >= 0) && (x0 < WW);
    bool vx1 = (x1 >= 0) && (x1 < WW);
    int yc0 = min(max(y0, 0), HH - 1);
    int yc1 = min(max(y1, 0), HH - 1);
    int xc0 = min(max(x0, 0), WW - 1);
    int xc1 = min(max(x1, 0), WW - 1);
    float w00 = (1.f - dy) * (1.f - dx) * m;
    float w01 = (1.f - dy) * dx * m;
    float w10 = dy * (1.f - dx) * m;
    float w11 = dy * dx * m;
    if (!(vy0 && vx0)) w00 = 0.f;
    if (!(vy0 && vx1)) w01 = 0.f;
    if (!(vy1 && vx0)) w10 = 0.f;
    if (!(vy1 && vx1)) w11 = 0.f;
    int i00 = yc0 * WW + xc0;
    int i01 = yc0 * WW + xc1;
    int i10 = yc1 * WW + xc0;
    int i11 = yc1 * WW + xc1;
#pragma unroll
    for (int c = 0; c < 16; ++c) {
      const float* xc = xb + (size_t)c * HWW;
      float s = xc[i00] * w00 + xc[i01] * w01 + xc[i10] * w10 + xc[i11] * w11;
      const float* wck = wt + (size_t)(c * 9 + k) * 16;  // uniform
#pragma unroll
      for (int o = 0; o < 16; ++o)
        acc[o] = fmaf(s, wck[o], acc[o]);
    }
  }
#pragma unroll
  for (int o = 0; o < 16; ++o)
    out[((size_t)b * 16 + o) * HWW + pixel] = fmaxf(acc[o], 0.f);
}

extern "C" void kernel_launch(void* const* d_in, const int* in_sizes, int n_in,
                              void* d_out, int out_size, void* d_ws, size_t ws_size,
                              hipStream_t stream) {
  (void)in_sizes; (void)n_in; (void)out_size; (void)ws_size;
  const float* f_E = (const float*)d_in[0];
  const float* f_F = (const float*)d_in[1];
  const float* att_w1 = (const float*)d_in[2];
  const float* att_b1 = (const float*)d_in[3];
  const float* att_w2 = (const float*)d_in[4];
  const float* att_b2 = (const float*)d_in[5];
  const float* ref_w = (const float*)d_in[6];
  const float* ref_b = (const float*)d_in[7];
  const float* om_w1 = (const float*)d_in[8];
  const float* om_b1 = (const float*)d_in[9];
  const float* om_w2 = (const float*)d_in[10];
  const float* om_b2 = (const float*)d_in[11];
  const float* om_w3 = (const float*)d_in[12];
  const float* om_b3 = (const float*)d_in[13];
  const float* dcb_w = (const float*)d_in[14];
  const float* dcb_b = (const float*)d_in[15];
  const float* dcbref_w = (const float*)d_in[16];
  const float* dcbref_b = (const float*)d_in[17];
  const float* fin_w = (const float*)d_in[18];
  const float* fin_b = (const float*)d_in[19];
  float* outp = (float*)d_out;

  const size_t T16 = (size_t)4 * 16 * HWW;   // one 16-ch fp32 tensor (floats)
  const size_t T27 = (size_t)4 * 27 * HWW;
  float* R0 = (float*)d_ws;     // conv_a, later om_t3
  float* R1 = R0 + T16;         // f_Esa, later f_Edc
  float* R2 = R1 + T16;         // f_EFsa
  float* R3 = R2 + T16;         // om_t2, later f_EFdc
  float* R4 = R3 + T16;         // om (27 ch)
  float* WT = R4 + T27;         // repacked weights

  float* WT0 = WT;                // att_w1  32x16
  float* WT1 = WT0 + 32 * 16 * 9; // att_w2  16x1
  float* WT2 = WT1 + 16 * 1 * 9;  // ref_w   32x16
  float* WT3 = WT2 + 32 * 16 * 9; // om_w1   32x16
  float* WT4 = WT3 + 32 * 16 * 9; // om_w2   16x16
  float* WT5 = WT4 + 16 * 16 * 9; // om_w3   16x27
  float* WT6 = WT5 + 16 * 27 * 9; // dcb_w   16x16
  float* WT7 = WT6 + 16 * 16 * 9; // dcbref  32x16
  float* WT8 = WT7 + 32 * 16 * 9; // fin_w   32x16

  RepackArgs ra;
  ra.d[0] = {att_w1, WT0, 32, 16};
  ra.d[1] = {att_w2, WT1, 16, 1};
  ra.d[2] = {ref_w, WT2, 32, 16};
  ra.d[3] = {om_w1, WT3, 32, 16};
  ra.d[4] = {om_w2, WT4, 16, 16};
  ra.d[5] = {om_w3, WT5, 16, 27};
  ra.d[6] = {dcb_w, WT6, 16, 16};
  ra.d[7] = {dcbref_w, WT7, 32, 16};
  ra.d[8] = {fin_w, WT8, 32, 16};
  repack_k<<<dim3(9), dim3(256), 0, stream>>>(ra);

  dim3 blk(256);
  dim3 gc(WW / 32, HH / 8, 4);   // 8 x 32 x 4 = 1024 blocks

  // K1: conv_a = relu(conv(cat(f_E,f_F), att_w1))
  conv_v2<32, 16, 1, false><<<gc, blk, 0, stream>>>(f_E, f_F, WT0, att_b1, nullptr, R0);
  // K2: f_Esa = f_E * sigmoid(conv(conv_a, att_w2))
  conv_v2<16, 1, 0, true><<<gc, blk, 0, stream>>>(R0, nullptr, WT1, att_b2, f_E, R1);
  // K3: f_EFsa = relu(conv(cat(f_Esa,f_F), ref_w))
  conv_v2<32, 16, 1, false><<<gc, blk, 0, stream>>>(R1, f_F, WT2, ref_b, nullptr, R2);
  // K4: om_t2 = relu(conv(cat(f_E,f_F), om_w1))
  conv_v2<32, 16, 1, false><<<gc, blk, 0, stream>>>(f_E, f_F, WT3, om_b1, nullptr, R3);
  // K5: om_t3 = relu(conv(om_t2, om_w2))
  conv_v2<16, 16, 1, false><<<gc, blk, 0, stream>>>(R3, nullptr, WT4, om_b2, nullptr, R0);
  // K6: om = conv(om_t3, om_w3)   (raw; 27 ch)
  conv_v2<16, 27, 0, false><<<gc, blk, 0, stream>>>(R0, nullptr, WT5, om_b3, nullptr, R4);
  // K7: f_Edc = relu(deform_conv(f_E, om, dcb_w))
  deform_v2<<<dim3(HWW / 256, 1, 4), blk, 0, stream>>>(f_E, R4, WT6, dcb_b, R1);
  // K8: f_EFdc = relu(conv(cat(f_Edc,f_F), dcbref_w))
  conv_v2<32, 16, 1, false><<<gc, blk, 0, stream>>>(R1, f_F, WT7, dcbref_b, nullptr, R3);
  // K9: out = relu(conv(cat(f_EFsa,f_EFdc), fin_w))
  conv_v2<32, 16, 1, false><<<gc, blk, 0, stream>>>(R2, R3, WT8, fin_b, nullptr, outp);
}

// Round 3
// 227.961 us; speedup vs baseline: 5.9724x; 2.0189x over previous
//
#include <hip/hip_runtime.h>
#include <cstdint>
#include <cstddef>

#define HH 256
#define WW 256
#define HWW (HH * WW)

typedef __attribute__((ext_vector_type(8))) short bf16x8;
typedef __attribute__((ext_vector_type(4))) float f32x4;

__device__ inline unsigned short f2bf(float f) {
  unsigned u = __float_as_uint(f);
  unsigned r = (u + 0x7fffu + ((u >> 16) & 1u)) >> 16;
  return (unsigned short)r;
}
__device__ inline float bf2f(unsigned short u) {
  return __uint_as_float((unsigned)u << 16);
}
__device__ inline float bf_lo(unsigned w) { return __uint_as_float(w << 16); }
__device__ inline float bf_hi(unsigned w) { return __uint_as_float(w & 0xffff0000u); }

// ---------------------------------------------------------------------------
// Weight repack.
// mode 0: [cin][9][cout] fp32            (scalar-conv path, K2)
// mode 1: [k][cin][cout] fp32            (deform)
// mode 2: MFMA B-fragment pack, bf16:    dst[((ot*NST+s)*64+l)*8+j]
//         o = ot*16 + (l&15); klin = s*32 + (l>>4)*8 + j; tap = klin/cin,
//         c = klin%cin; val = (tap<9 && o<cout) ? W[o][c][tap] : 0
// ---------------------------------------------------------------------------
struct RD { const float* src; void* dst; int cin, cout, mode; };
struct RA { RD d[10]; };

__global__ __launch_bounds__(256) void repack_k(RA a) {
  const RD t = a.d[blockIdx.x];
  if (t.mode == 2) {
    const int NST = (t.cin * 9 + 31) / 32;
    const int OT = (t.cout + 15) / 16;
    const int n = OT * NST * 512;
    unsigned short* dst = (unsigned short*)t.dst;
    for (int i = threadIdx.x; i < n; i += 256) {
      int j = i & 7;
      int l = (i >> 3) & 63;
      int rest = i >> 9;
      int s = rest % NST;
      int ot = rest / NST;
      int o = ot * 16 + (l & 15);
      int klin = s * 32 + ((l >> 4) << 3) + j;
      int tap = klin / t.cin;
      int c = klin % t.cin;
      float v = 0.f;
      if (tap < 9 && o < t.cout) v = t.src[(o * t.cin + c) * 9 + tap];
      dst[i] = f2bf(v);
    }
  } else {
    float* dst = (float*)t.dst;
    const int n = t.cin * t.cout * 9;
    for (int i = threadIdx.x; i < n; i += 256) {
      int k = i % 9;
      int rest = i / 9;
      int c = rest % t.cin;
      int o = rest / t.cin;
      if (t.mode == 0) dst[(c * 9 + k) * t.cout + o] = t.src[(o * t.cin + c) * 9 + k];
      else             dst[(k * t.cin + c) * t.cout + o] = t.src[(o * t.cin + c) * 9 + k];
    }
  }
}

// ---------------------------------------------------------------------------
// f_E (fp32 NCHW) -> bf16 NHWC [B][H][W][16] for deform gathers.
// ---------------------------------------------------------------------------
__global__ __launch_bounds__(256) void nhwc_k(const float* __restrict__ x,
                                              unsigned short* __restrict__ xn) {
  const int b = blockIdx.z;
  const int pixel = blockIdx.x * 256 + threadIdx.x;
  unsigned w[8];
#pragma unroll
  for (int j = 0; j < 8; ++j) {
    unsigned short lo = f2bf(x[((size_t)b * 16 + 2 * j) * HWW + pixel]);
    unsigned short hi = f2bf(x[((size_t)b * 16 + 2 * j + 1) * HWW + pixel]);
    w[j] = (unsigned)lo | ((unsigned)hi << 16);
  }
  uint4* dst = (uint4*)(xn + ((size_t)b * HWW + pixel) * 16);
  dst[0] = make_uint4(w[0], w[1], w[2], w[3]);
  dst[1] = make_uint4(w[4], w[5], w[6], w[7]);
}

// ---------------------------------------------------------------------------
// MFMA implicit-GEMM 3x3 conv, stride 1, pad 1. fp32 NCHW in, bf16 compute.
// Block: 256 thr (4 waves), tile 64x8 px. LDS: bf16 NHWC [10][66][CIN],
// channel-group slot XOR-swizzled by pixel-index low bits.
// D[m=px16][n=o16] via mfma_f32_16x16x32_bf16; K-order = tap*CIN + c.
// OUT_MODE 0: fp32 NCHW + ReLU. OUT_MODE 1: bf16 NCHW planes, raw (om).
// ---------------------------------------------------------------------------
template <int CIN, int OT, int OUT_MODE, int COUTR>
__global__ __launch_bounds__(256) void conv_mfma(
    const float* __restrict__ inA, const float* __restrict__ inB,
    const unsigned short* __restrict__ wtm, const float* __restrict__ bias,
    void* __restrict__ outv) {
  constexpr int PX = 66, PY = 10;
  constexpr int NG = CIN / 8;                 // LDS 16B slots per pixel
  constexpr int NST = (CIN * 9 + 31) / 32;    // K-steps
  constexpr int STRIDE = CIN * 2;             // bytes per pixel in LDS
  __shared__ __align__(16) char smem[PY * PX * CIN * 2];

  const int b = blockIdx.z;
  const int tx0 = blockIdx.x * 64;
  const int ty0 = blockIdx.y * 8;
  const int tid = threadIdx.x;
  const int lane = tid & 63;
  const int wv = tid >> 6;

  // ---- B fragments (whole kernel, VGPR-resident) ----
  bf16x8 bfr[OT][NST];
#pragma unroll
  for (int ot = 0; ot < OT; ++ot)
#pragma unroll
    for (int s = 0; s < NST; ++s)
      bfr[ot][s] = *(const bf16x8*)(wtm + (size_t)(((ot * NST + s) * 64 + lane) * 8));

  // ---- accumulators ----
  f32x4 acc[8][OT];
  {
#pragma unroll
    for (int ot = 0; ot < OT; ++ot) {
      int o = ot * 16 + (lane & 15);
      float bv = bias[o < COUTR ? o : COUTR - 1];
#pragma unroll
      for (int t = 0; t < 8; ++t) acc[t][ot] = f32x4{bv, bv, bv, bv};
    }
  }

  // ---- stage input tile: fp32 NCHW -> bf16 NHWC swizzled LDS ----
  for (int i = tid; i < NG * PY * PX; i += 256) {
    int pp = i % (PY * PX);
    int g = i / (PY * PX);
    int ly = pp / PX;
    int lx = pp - ly * PX;
    int gy = ty0 + ly - 1;
    int gx = tx0 + lx - 1;
    bool ok = (gy >= 0) && (gy < HH) && (gx >= 0) && (gx < WW);
    unsigned w[4];
#pragma unroll
    for (int j = 0; j < 4; ++j) {
      unsigned short lo = 0, hi = 0;
      if (ok) {
        int c0 = g * 8 + 2 * j;
        const float* s0 = inA; int cl0 = c0;
        if (CIN == 32 && c0 >= 16) { s0 = inB; cl0 = c0 - 16; }
        const float* s1 = inA; int cl1 = c0 + 1;
        if (CIN == 32 && c0 + 1 >= 16) { s1 = inB; cl1 = c0 + 1 - 16; }
        lo = f2bf(s0[((size_t)b * 16 + cl0) * HWW + gy * WW + gx]);
        hi = f2bf(s1[((size_t)b * 16 + cl1) * HWW + gy * WW + gx]);
      }
      w[j] = (unsigned)lo | ((unsigned)hi << 16);
    }
    char* dst = smem + (size_t)pp * STRIDE + (size_t)((g ^ (pp & (NG - 1))) << 4);
    *(uint4*)dst = make_uint4(w[0], w[1], w[2], w[3]);
  }
  __syncthreads();

  // ---- per-lane A-read geometry (loop-invariant over tiles) ----
  const int xr = lane & 15;
  const int g4 = lane >> 4;
  int dpix[NST], dslot[NST];
#pragma unroll
  for (int s = 0; s < NST; ++s) {
    int klin = s * 32 + g4 * 8;
    int tap = klin / CIN;
    if (tap > 8) tap = 8;                       // dummy region (zero weights)
    int coff = klin % CIN;
    int ky = tap / 3, kx = tap - ky * 3;
    dpix[s] = ky * PX + kx;
    dslot[s] = coff >> 3;
  }

  // ---- main MFMA loop: 8 px-tiles per wave ----
  const int oy_l = wv * 2;
#pragma unroll
  for (int t = 0; t < 8; ++t) {
    const int base_pix = (oy_l + (t >> 2)) * PX + (t & 3) * 16 + xr;
#pragma unroll
    for (int s = 0; s < NST; ++s) {
      int pp = base_pix + dpix[s];
      int byteoff = pp * STRIDE + ((dslot[s] ^ (pp & (NG - 1))) << 4);
      bf16x8 av = *(const bf16x8*)(smem + byteoff);
#pragma unroll
      for (int ot = 0; ot < OT; ++ot)
        acc[t][ot] = __builtin_amdgcn_mfma_f32_16x16x32_bf16(av, bfr[ot][s], acc[t][ot], 0, 0, 0);
    }
  }

  // ---- epilogue ----
#pragma unroll
  for (int t = 0; t < 8; ++t) {
    const int ty_g = ty0 + oy_l + (t >> 2);
    const int xg = tx0 + (t & 3) * 16 + g4 * 4;
#pragma unroll
    for (int ot = 0; ot < OT; ++ot) {
      const int o = ot * 16 + (lane & 15);
      if (o < COUTR) {
#pragma unroll
        for (int r = 0; r < 4; ++r) {
          float v = acc[t][ot][r];
          size_t idx = ((size_t)b * COUTR + o) * HWW + (size_t)ty_g * WW + xg + r;
          if (OUT_MODE == 0) ((float*)outv)[idx] = fmaxf(v, 0.f);
          else               ((unsigned short*)outv)[idx] = f2bf(v);
        }
      }
    }
  }
}

// ---------------------------------------------------------------------------
// Scalar conv (K2 only): 16 -> 1 + sigmoid gate fused multiply.
// Weights [cin][9][cout] fp32 (mode 0).
// ---------------------------------------------------------------------------
__global__ __launch_bounds__(256) void conv_gate_k(
    const float* __restrict__ inA, const float* __restrict__ wt,
    const float* __restrict__ bias, const float* __restrict__ gsrc,
    float* __restrict__ out) {
  constexpr int TX = 32, TY = 8;
  constexpr int PX = TX + 2, PY = TY + 2;
  constexpr int CHUNK = 8;
  __shared__ float s_in[CHUNK][PY * PX];

  const int b = blockIdx.z;
  const int tx0 = blockIdx.x * TX;
  const int ty0 = blockIdx.y * TY;
  const int tid = threadIdx.x;
  const int thx = tid & 31;
  const int thy = tid >> 5;

  float acc = bias[0];
  for (int c0 = 0; c0 < 16; c0 += CHUNK) {
    __syncthreads();
    for (int i = tid; i < CHUNK * PY * PX; i += 256) {
      int cc = i / (PY * PX);
      int pos = i - cc * (PY * PX);
      int iy = pos / PX;
      int ix = pos - iy * PX;
      int gy = ty0 + iy - 1;
      int gx = tx0 + ix - 1;
      float v = 0.f;
      if (gy >= 0 && gy < HH && gx >= 0 && gx < WW)
        v = inA[((size_t)b * 16 + c0 + cc) * HWW + gy * WW + gx];
      s_in[cc][pos] = v;
    }
    __syncthreads();
#pragma unroll
    for (int cc = 0; cc < CHUNK; ++cc) {
      const float* wc = wt + (size_t)(c0 + cc) * 9;
#pragma unroll
      for (int wy = 0; wy < 3; ++wy)
#pragma unroll
        for (int wx = 0; wx < 3; ++wx)
          acc = fmaf(s_in[cc][(thy + wy) * PX + thx + wx], wc[wy * 3 + wx], acc);
    }
  }
  const int oy = ty0 + thy;
  const int ox = tx0 + thx;
  float m = 1.0f / (1.0f + expf(-acc));
#pragma unroll
  for (int c = 0; c < 16; ++c) {
    size_t idx = ((size_t)b * 16 + c) * HWW + (size_t)oy * WW + ox;
    out[idx] = gsrc[idx] * m;
  }
}

// ---------------------------------------------------------------------------
// Modulated deformable conv 3x3, 16->16, + ReLU.
// x: bf16 NHWC [B][H][W][16]; om: bf16 NCHW planes [B][27][HW];
// weights [k][c][o] fp32. XCD-aware swizzle: batch b pinned to XCDs {2b,2b+1}.
// ---------------------------------------------------------------------------
__global__ __launch_bounds__(256) void deform_v3(
    const unsigned short* __restrict__ xn, const unsigned short* __restrict__ om,
    const float* __restrict__ wt, const float* __restrict__ bias,
    float* __restrict__ out) {
  const int bid = blockIdx.x;
  const int xcd = bid & 7;
  const int b = xcd >> 1;
  const int pb = ((bid >> 3) << 1) | (xcd & 1);
  const int pixel = pb * 256 + (int)threadIdx.x;
  const int y = pixel >> 8;
  const int xq = pixel & 255;
  const unsigned short* xb = xn + (size_t)b * HWW * 16;
  const unsigned short* omb = om + (size_t)b * 27 * HWW;

  float acc[16];
#pragma unroll
  for (int o = 0; o < 16; ++o) acc[o] = bias[o];

#pragma unroll
  for (int k = 0; k < 9; ++k) {
    float offy = bf2f(omb[(size_t)(2 * k) * HWW + pixel]);
    float offx = bf2f(omb[(size_t)(2 * k + 1) * HWW + pixel]);
    float m = 1.0f / (1.0f + expf(-bf2f(omb[(size_t)(18 + k) * HWW + pixel])));
    float py = (float)y + (float)(k / 3 - 1) + offy;
    float px = (float)xq + (float)(k % 3 - 1) + offx;
    float y0f = floorf(py);
    float x0f = floorf(px);
    float dy = py - y0f;
    float dx = px - x0f;
    int y0 = (int)y0f, x0 = (int)x0f;
    int y1 = y0 + 1, x1 = x0 + 1;
    bool vy0 = (y0 >= 0) && (y0 < HH);
    bool vy1 = (y1 >= 0) && (y1 < HH);
    bool vx0 = (x0 >= 0) && (x0 < WW);
    bool vx1 = (x1 >= 0) && (x1 < WW);
    int yc0 = min(max(y0, 0), HH - 1);
    int yc1 = min(max(y1, 0), HH - 1);
    int xc0 = min(max(x0, 0), WW - 1);
    int xc1 = min(max(x1, 0), WW - 1);
    float w00 = (1.f - dy) * (1.f - dx) * m;
    float w01 = (1.f - dy) * dx * m;
    float w10 = dy * (1.f - dx) * m;
    float w11 = dy * dx * m;
    if (!(vy0 && vx0)) w00 = 0.f;
    if (!(vy0 && vx1)) w01 = 0.f;
    if (!(vy1 && vx0)) w10 = 0.f;
    if (!(vy1 && vx1)) w11 = 0.f;

    const uint4* p00 = (const uint4*)(xb + (size_t)(yc0 * WW + xc0) * 16);
    const uint4* p01 = (const uint4*)(xb + (size_t)(yc0 * WW + xc1) * 16);
    const uint4* p10 = (const uint4*)(xb + (size_t)(yc1 * WW + xc0) * 16);
    const uint4* p11 = (const uint4*)(xb + (size_t)(yc1 * WW + xc1) * 16);
    uint4 a0 = p00[0], a1 = p00[1];
    uint4 b0 = p01[0], b1 = p01[1];
    uint4 c0 = p10[0], c1 = p10[1];
    uint4 d0 = p11[0], d1 = p11[1];
    unsigned wA[8] = {a0.x, a0.y, a0.z, a0.w, a1.x, a1.y, a1.z, a1.w};
    unsigned wB[8] = {b0.x, b0.y, b0.z, b0.w, b1.x, b1.y, b1.z, b1.w};
    unsigned wC[8] = {c0.x, c0.y, c0.z, c0.w, c1.x, c1.y, c1.z, c1.w};
    unsigned wD[8] = {d0.x, d0.y, d0.z, d0.w, d1.x, d1.y, d1.z, d1.w};

    float s[16];
#pragma unroll
    for (int j = 0; j < 8; ++j) {
      s[2 * j] = bf_lo(wA[j]) * w00 + bf_lo(wB[j]) * w01 + bf_lo(wC[j]) * w10 + bf_lo(wD[j]) * w11;
      s[2 * j + 1] = bf_hi(wA[j]) * w00 + bf_hi(wB[j]) * w01 + bf_hi(wC[j]) * w10 + bf_hi(wD[j]) * w11;
    }
    const float* wk = wt + (size_t)k * 256;
#pragma unroll
    for (int c = 0; c < 16; ++c)
#pragma unroll
      for (int o = 0; o < 16; ++o)
        acc[o] = fmaf(s[c], wk[c * 16 + o], acc[o]);
  }
#pragma unroll
  for (int o = 0; o < 16; ++o)
    out[((size_t)b * 16 + o) * HWW + pixel] = fmaxf(acc[o], 0.f);
}

extern "C" void kernel_launch(void* const* d_in, const int* in_sizes, int n_in,
                              void* d_out, int out_size, void* d_ws, size_t ws_size,
                              hipStream_t stream) {
  (void)in_sizes; (void)n_in; (void)out_size; (void)ws_size;
  const float* f_E = (const float*)d_in[0];
  const float* f_F = (const float*)d_in[1];
  const float* att_w1 = (const float*)d_in[2];
  const float* att_b1 = (const float*)d_in[3];
  const float* att_w2 = (const float*)d_in[4];
  const float* att_b2 = (const float*)d_in[5];
  const float* ref_w = (const float*)d_in[6];
  const float* ref_b = (const float*)d_in[7];
  const float* om_w1 = (const float*)d_in[8];
  const float* om_b1 = (const float*)d_in[9];
  const float* om_w2 = (const float*)d_in[10];
  const float* om_b2 = (const float*)d_in[11];
  const float* om_w3 = (const float*)d_in[12];
  const float* om_b3 = (const float*)d_in[13];
  const float* dcb_w = (const float*)d_in[14];
  const float* dcb_b = (const float*)d_in[15];
  const float* dcbref_w = (const float*)d_in[16];
  const float* dcbref_b = (const float*)d_in[17];
  const float* fin_w = (const float*)d_in[18];
  const float* fin_b = (const float*)d_in[19];
  float* outp = (float*)d_out;

  const size_t T16 = (size_t)4 * 16 * HWW;          // fp32 activation elems
  float* R0 = (float*)d_ws;
  float* R1 = R0 + T16;
  float* R2 = R1 + T16;
  float* R3 = R2 + T16;
  unsigned short* OMB = (unsigned short*)(R3 + T16);          // bf16 om planes
  unsigned short* XN = OMB + (size_t)4 * 27 * HWW;            // bf16 NHWC f_E
  unsigned short* WM = XN + (size_t)4 * 16 * HWW;             // weight area

  unsigned short* WM_att1 = WM;                 // mode2 CIN32 OT1: 4608 ush
  unsigned short* WM_ref  = WM_att1 + 4608;
  unsigned short* WM_om1  = WM_ref + 4608;
  unsigned short* WM_om2  = WM_om1 + 4608;      // CIN16 OT1: 2560
  unsigned short* WM_om3  = WM_om2 + 2560;      // CIN16 OT2: 5120
  unsigned short* WM_dref = WM_om3 + 5120;
  unsigned short* WM_fin  = WM_dref + 4608;
  float* WF_att2 = (float*)(WM_fin + 4608);     // mode0: 144 f
  float* WF_dcb  = WF_att2 + 144;               // mode1: 2304 f

  RA ra;
  ra.d[0] = {att_w1, WM_att1, 32, 16, 2};
  ra.d[1] = {ref_w, WM_ref, 32, 16, 2};
  ra.d[2] = {om_w1, WM_om1, 32, 16, 2};
  ra.d[3] = {om_w2, WM_om2, 16, 16, 2};
  ra.d[4] = {om_w3, WM_om3, 16, 27, 2};
  ra.d[5] = {dcbref_w, WM_dref, 32, 16, 2};
  ra.d[6] = {fin_w, WM_fin, 32, 16, 2};
  ra.d[7] = {att_w2, WF_att2, 16, 1, 0};
  ra.d[8] = {dcb_w, WF_dcb, 16, 16, 1};
  ra.d[9] = {att_w2, WF_att2, 16, 1, 0};  // dup (harmless)
  repack_k<<<dim3(10), dim3(256), 0, stream>>>(ra);
  nhwc_k<<<dim3(HWW / 256, 1, 4), dim3(256), 0, stream>>>(f_E, XN);

  dim3 blk(256);
  dim3 gm(WW / 64, HH / 8, 4);   // 4 x 32 x 4 = 512 blocks
  dim3 gs(WW / 32, HH / 8, 4);   // scalar conv grid

  // K1: conv_a = relu(conv(cat(f_E,f_F), att_w1))
  conv_mfma<32, 1, 0, 16><<<gm, blk, 0, stream>>>(f_E, f_F, WM_att1, att_b1, R0);
  // K2: f_Esa = f_E * sigmoid(conv(conv_a, att_w2))
  conv_gate_k<<<gs, blk, 0, stream>>>(R0, WF_att2, att_b2, f_E, R1);
  // K3: f_EFsa = relu(conv(cat(f_Esa,f_F), ref_w))
  conv_mfma<32, 1, 0, 16><<<gm, blk, 0, stream>>>(R1, f_F, WM_ref, ref_b, R2);
  // K4: om_t2 = relu(conv(cat(f_E,f_F), om_w1))
  conv_mfma<32, 1, 0, 16><<<gm, blk, 0, stream>>>(f_E, f_F, WM_om1, om_b1, R3);
  // K5: om_t3 = relu(conv(om_t2, om_w2))
  conv_mfma<16, 1, 0, 16><<<gm, blk, 0, stream>>>(R3, nullptr, WM_om2, om_b2, R0);
  // K6: om = conv(om_t3, om_w3)  raw, bf16 planes
  conv_mfma<16, 2, 1, 27><<<gm, blk, 0, stream>>>(R0, nullptr, WM_om3, om_b3, OMB);
  // K7: f_Edc = relu(deform_conv(f_E, om, dcb_w))
  deform_v3<<<dim3(1024), blk, 0, stream>>>(XN, OMB, WF_dcb, dcb_b, R1);
  // K8: f_EFdc = relu(conv(cat(f_Edc,f_F), dcbref_w))
  conv_mfma<32, 1, 0, 16><<<gm, blk, 0, stream>>>(R1, f_F, WM_dref, dcbref_b, R3);
  // K9: out = relu(conv(cat(f_EFsa,f_EFdc), fin_w))
  conv_mfma<32, 1, 0, 16><<<gm, blk, 0, stream>>>(R2, R3, WM_fin, fin_b, outp);
}

// Round 4
// 128.769 us; speedup vs baseline: 10.5729x; 1.7703x over previous
//
#include <hip/hip_runtime.h>
#include <cstdint>
#include <cstddef>

#define HH 256
#define WW 256
#define HWW (HH * WW)

typedef __attribute__((ext_vector_type(8))) short bf16x8;
typedef __attribute__((ext_vector_type(4))) float f32x4;
typedef unsigned short ushort_t;

__device__ inline unsigned short f2bf(float f) {
  unsigned u = __float_as_uint(f);
  unsigned r = (u + 0x7fffu + ((u >> 16) & 1u)) >> 16;
  return (unsigned short)r;
}
__device__ inline float bf2f(unsigned short u) {
  return __uint_as_float((unsigned)u << 16);
}
__device__ inline float bf_lo(unsigned w) { return __uint_as_float(w << 16); }
__device__ inline float bf_hi(unsigned w) { return __uint_as_float(w & 0xffff0000u); }

// ---------------------------------------------------------------------------
// Weight repack.
// mode 0: [cin][9][cout] fp32                     (gate conv K2)
// mode 1: [k][cin][cout] fp32                     (deform)
// mode 2: MFMA A-fragment pack (weights are the A operand), bf16:
//   dst[((ot*NST+s)*64+l)*8+j]: o = ot*16+(l&15); klin = s*32+(l>>4)*8+j;
//   tap=klin/cin, c=klin%cin; val = (tap<9 && o<cout) ? W[o][c][tap] : 0
// ---------------------------------------------------------------------------
struct RD { const float* src; void* dst; int cin, cout, mode; };
struct RA { RD d[9]; };

__global__ __launch_bounds__(256) void repack_k(RA a) {
  const RD t = a.d[blockIdx.x];
  if (t.mode == 2) {
    const int NST = (t.cin * 9 + 31) / 32;
    const int OT = (t.cout + 15) / 16;
    const int n = OT * NST * 512;
    unsigned short* dst = (unsigned short*)t.dst;
    for (int i = threadIdx.x; i < n; i += 256) {
      int j = i & 7;
      int l = (i >> 3) & 63;
      int rest = i >> 9;
      int s = rest % NST;
      int ot = rest / NST;
      int o = ot * 16 + (l & 15);
      int klin = s * 32 + ((l >> 4) << 3) + j;
      int tap = klin / t.cin;
      int c = klin % t.cin;
      float v = 0.f;
      if (tap < 9 && o < t.cout) v = t.src[(o * t.cin + c) * 9 + tap];
      dst[i] = f2bf(v);
    }
  } else {
    float* dst = (float*)t.dst;
    const int n = t.cin * t.cout * 9;
    for (int i = threadIdx.x; i < n; i += 256) {
      int k = i % 9;
      int rest = i / 9;
      int c = rest % t.cin;
      int o = rest / t.cin;
      if (t.mode == 0) dst[(c * 9 + k) * t.cout + o] = t.src[(o * t.cin + c) * 9 + k];
      else             dst[(k * t.cin + c) * t.cout + o] = t.src[(o * t.cin + c) * 9 + k];
    }
  }
}

// ---------------------------------------------------------------------------
// f_E, f_F (fp32 NCHW) -> bf16 NHWC [B][H][W][16].
// ---------------------------------------------------------------------------
__global__ __launch_bounds__(256) void nhwc2_k(
    const float* __restrict__ fe, const float* __restrict__ ff,
    unsigned short* __restrict__ xe, unsigned short* __restrict__ xf) {
  const int b = blockIdx.z;
  const int pixel = blockIdx.x * 256 + threadIdx.x;
#pragma unroll
  for (int t = 0; t < 2; ++t) {
    const float* src = t ? ff : fe;
    unsigned short* dst = t ? xf : xe;
    unsigned w[8];
#pragma unroll
    for (int j = 0; j < 8; ++j) {
      unsigned short lo = f2bf(src[((size_t)b * 16 + 2 * j) * HWW + pixel]);
      unsigned short hi = f2bf(src[((size_t)b * 16 + 2 * j + 1) * HWW + pixel]);
      w[j] = (unsigned)lo | ((unsigned)hi << 16);
    }
    uint4* d4 = (uint4*)(dst + ((size_t)b * HWW + pixel) * 16);
    d4[0] = make_uint4(w[0], w[1], w[2], w[3]);
    d4[1] = make_uint4(w[4], w[5], w[6], w[7]);
  }
}

// ---------------------------------------------------------------------------
// MFMA implicit-GEMM 3x3 conv, bf16 NHWC in. Tile 64x8 px, 256 thr (4 waves).
// Weights = A operand (m=o), activations = B operand (n=pixel):
// D col(lane&15)=pixel, row((lane>>4)*4+r)=o -> NHWC epilogue is 8B/lane.
// NSLOT = CIN/8 LDS 16B slots per pixel; slot XOR-swizzled for 2-way banks.
// OUT_MODE 0: fp32 NCHW + ReLU (final). 1: bf16 NCHW planes raw (om).
//          2: bf16 NHWC + ReLU (default intermediate).
// ---------------------------------------------------------------------------
template <int NSLOT, int OT, int OUT_MODE, int COUTR>
__global__ __launch_bounds__(256) void conv_nhwc(
    const unsigned short* __restrict__ inA, const unsigned short* __restrict__ inB,
    const unsigned short* __restrict__ wtm, const float* __restrict__ bias,
    void* __restrict__ outv) {
  constexpr int CIN = NSLOT * 8;
  constexpr int NST = (CIN * 9 + 31) / 32;
  constexpr int SHIFT = (NSLOT == 4) ? 1 : 2;   // bank-decorrelation bits
  constexpr int STRIDE = NSLOT * 16;            // bytes per pixel in LDS
  constexpr int PX = 66, PY = 10;
  __shared__ __align__(16) char smem[PY * PX * STRIDE];

  const int b = blockIdx.z;
  const int tx0 = blockIdx.x * 64;
  const int ty0 = blockIdx.y * 8;
  const int tid = threadIdx.x;
  const int lane = tid & 63;
  const int wv = tid >> 6;

  // ---- A fragments: weights, VGPR-resident ----
  bf16x8 afr[OT][NST];
#pragma unroll
  for (int ot = 0; ot < OT; ++ot)
#pragma unroll
    for (int s = 0; s < NST; ++s)
      afr[ot][s] = *(const bf16x8*)(wtm + (size_t)(((ot * NST + s) * 64 + lane) * 8));

  const int px_l = lane & 15;
  const int og = lane >> 4;

  // ---- accumulators (bias; row = o) ----
  f32x4 acc[8][OT];
#pragma unroll
  for (int ot = 0; ot < OT; ++ot) {
    f32x4 bv;
#pragma unroll
    for (int r = 0; r < 4; ++r) {
      int o = ot * 16 + og * 4 + r;
      bv[r] = bias[o < COUTR ? o : COUTR - 1];
    }
#pragma unroll
    for (int t = 0; t < 8; ++t) acc[t][ot] = bv;
  }

  // ---- stage input tile (bf16 NHWC -> swizzled LDS) ----
  for (int i = tid; i < PY * PX * NSLOT; i += 256) {
    int pp = i / NSLOT;
    int s = i - pp * NSLOT;
    int ly = pp / PX;
    int lx = pp - ly * PX;
    int gy = ty0 + ly - 1;
    int gx = tx0 + lx - 1;
    uint4 v = make_uint4(0, 0, 0, 0);
    if (gy >= 0 && gy < HH && gx >= 0 && gx < WW) {
      const unsigned short* src = (NSLOT == 2 || s < 2) ? inA : inB;
      int sl = (NSLOT == 4 && s >= 2) ? s - 2 : s;
      v = *(const uint4*)(src + ((size_t)b * HWW + (size_t)gy * WW + gx) * 16 + sl * 8);
    }
    int swz = (s ^ (pp >> SHIFT)) & (NSLOT - 1);
    *(uint4*)(smem + (size_t)pp * STRIDE + (swz << 4)) = v;
  }
  __syncthreads();

  // ---- per-lane B-read geometry ----
  int dpix[NST], dslot[NST];
#pragma unroll
  for (int s = 0; s < NST; ++s) {
    int klin = s * 32 + og * 8;
    int tap = klin / CIN;
    if (tap > 8) tap = 8;                    // dummy region (zero weights)
    int coff = klin % CIN;
    dpix[s] = (tap / 3) * PX + (tap % 3);
    dslot[s] = coff >> 3;
  }

  // ---- main MFMA loop ----
  const int oy_l = wv * 2;
#pragma unroll
  for (int t = 0; t < 8; ++t) {
    const int base_pix = (oy_l + (t >> 2)) * PX + (t & 3) * 16 + px_l;
#pragma unroll
    for (int s = 0; s < NST; ++s) {
      int pp = base_pix + dpix[s];
      int off = pp * STRIDE + (((dslot[s] ^ (pp >> SHIFT)) & (NSLOT - 1)) << 4);
      bf16x8 bvv = *(const bf16x8*)(smem + off);
#pragma unroll
      for (int ot = 0; ot < OT; ++ot)
        acc[t][ot] = __builtin_amdgcn_mfma_f32_16x16x32_bf16(afr[ot][s], bvv, acc[t][ot], 0, 0, 0);
    }
  }

  // ---- epilogue ----
#pragma unroll
  for (int t = 0; t < 8; ++t) {
    const int gy = ty0 + oy_l + (t >> 2);
    const int gx = tx0 + (t & 3) * 16 + px_l;
#pragma unroll
    for (int ot = 0; ot < OT; ++ot) {
      const int o0 = ot * 16 + og * 4;
      if (OUT_MODE == 2) {
        unsigned lo = (unsigned)f2bf(fmaxf(acc[t][ot][0], 0.f)) |
                      ((unsigned)f2bf(fmaxf(acc[t][ot][1], 0.f)) << 16);
        unsigned hi = (unsigned)f2bf(fmaxf(acc[t][ot][2], 0.f)) |
                      ((unsigned)f2bf(fmaxf(acc[t][ot][3], 0.f)) << 16);
        uint2* dst = (uint2*)((unsigned short*)outv +
                              ((size_t)b * HWW + (size_t)gy * WW + gx) * 16 + o0);
        *dst = make_uint2(lo, hi);
      } else if (OUT_MODE == 0) {
#pragma unroll
        for (int r = 0; r < 4; ++r) {
          int o = o0 + r;
          if (o < COUTR)
            ((float*)outv)[((size_t)b * COUTR + o) * HWW + (size_t)gy * WW + gx] =
                fmaxf(acc[t][ot][r], 0.f);
        }
      } else {
#pragma unroll
        for (int r = 0; r < 4; ++r) {
          int o = o0 + r;
          if (o < COUTR)
            ((unsigned short*)outv)[((size_t)b * COUTR + o) * HWW + (size_t)gy * WW + gx] =
                f2bf(acc[t][ot][r]);
        }
      }
    }
  }
}

// ---------------------------------------------------------------------------
// Gate (K2): M = sigmoid(conv3x3(conv_a, w2)); f_Esa = f_E * M.
// conv_a, f_E, f_Esa all bf16 NHWC. One row per block; taps via L1.
// ---------------------------------------------------------------------------
__global__ __launch_bounds__(256) void gate_k(
    const unsigned short* __restrict__ xa, const unsigned short* __restrict__ xe,
    const float* __restrict__ wt, const float* __restrict__ bias,
    unsigned short* __restrict__ xsa) {
  const int b = blockIdx.z;
  const int y = blockIdx.x;
  const int x = threadIdx.x;
  float acc = bias[0];
#pragma unroll
  for (int ky = 0; ky < 3; ++ky) {
    int gy = y + ky - 1;
    if (gy < 0 || gy >= HH) continue;
#pragma unroll
    for (int kx = 0; kx < 3; ++kx) {
      int gx = x + kx - 1;
      if (gx < 0 || gx >= WW) continue;
      const int k = ky * 3 + kx;
      const uint4* p = (const uint4*)(xa + ((size_t)b * HWW + (size_t)gy * WW + gx) * 16);
      uint4 v0 = p[0], v1 = p[1];
      unsigned wv[8] = {v0.x, v0.y, v0.z, v0.w, v1.x, v1.y, v1.z, v1.w};
#pragma unroll
      for (int j = 0; j < 8; ++j) {
        acc = fmaf(bf_lo(wv[j]), wt[(2 * j) * 9 + k], acc);
        acc = fmaf(bf_hi(wv[j]), wt[(2 * j + 1) * 9 + k], acc);
      }
    }
  }
  float m = 1.0f / (1.0f + expf(-acc));
  const uint4* pe = (const uint4*)(xe + ((size_t)b * HWW + (size_t)y * WW + x) * 16);
  uint4 e0 = pe[0], e1 = pe[1];
  unsigned ev[8] = {e0.x, e0.y, e0.z, e0.w, e1.x, e1.y, e1.z, e1.w};
  unsigned r[8];
#pragma unroll
  for (int j = 0; j < 8; ++j) {
    unsigned short lo = f2bf(bf_lo(ev[j]) * m);
    unsigned short hi = f2bf(bf_hi(ev[j]) * m);
    r[j] = (unsigned)lo | ((unsigned)hi << 16);
  }
  uint4* d4 = (uint4*)(xsa + ((size_t)b * HWW + (size_t)y * WW + x) * 16);
  d4[0] = make_uint4(r[0], r[1], r[2], r[3]);
  d4[1] = make_uint4(r[4], r[5], r[6], r[7]);
}

// ---------------------------------------------------------------------------
// Modulated deformable conv 3x3, 16->16, + ReLU.
// x: bf16 NHWC; om: bf16 NCHW planes [B][27][HW]; weights [k][c][o] fp32.
// Output bf16 NHWC. XCD-aware swizzle: batch b pinned to XCDs {2b,2b+1}.
// ---------------------------------------------------------------------------
__global__ __launch_bounds__(256) void deform_v4(
    const unsigned short* __restrict__ xn, const unsigned short* __restrict__ om,
    const float* __restrict__ wt, const float* __restrict__ bias,
    unsigned short* __restrict__ out) {
  const int bid = blockIdx.x;
  const int xcd = bid & 7;
  const int b = xcd >> 1;
  const int pb = ((bid >> 3) << 1) | (xcd & 1);
  const int pixel = pb * 256 + (int)threadIdx.x;
  const int y = pixel >> 8;
  const int xq = pixel & 255;
  const unsigned short* xb = xn + (size_t)b * HWW * 16;
  const unsigned short* omb = om + (size_t)b * 27 * HWW;

  float acc[16];
#pragma unroll
  for (int o = 0; o < 16; ++o) acc[o] = bias[o];

#pragma unroll
  for (int k = 0; k < 9; ++k) {
    float offy = bf2f(omb[(size_t)(2 * k) * HWW + pixel]);
    float offx = bf2f(omb[(size_t)(2 * k + 1) * HWW + pixel]);
    float m = 1.0f / (1.0f + expf(-bf2f(omb[(size_t)(18 + k) * HWW + pixel])));
    float py = (float)y + (float)(k / 3 - 1) + offy;
    float px = (float)xq + (float)(k % 3 - 1) + offx;
    float y0f = floorf(py);
    float x0f = floorf(px);
    float dy = py - y0f;
    float dx = px - x0f;
    int y0 = (int)y0f, x0 = (int)x0f;
    int y1 = y0 + 1, x1 = x0 + 1;
    bool vy0 = (y0 >= 0) && (y0 < HH);
    bool vy1 = (y1 >= 0) && (y1 < HH);
    bool vx0 = (x0 >= 0) && (x0 < WW);
    bool vx1 = (x1 >= 0) && (x1 < WW);
    int yc0 = min(max(y0, 0), HH - 1);
    int yc1 = min(max(y1, 0), HH - 1);
    int xc0 = min(max(x0, 0), WW - 1);
    int xc1 = min(max(x1, 0), WW - 1);
    float w00 = (1.f - dy) * (1.f - dx) * m;
    float w01 = (1.f - dy) * dx * m;
    float w10 = dy * (1.f - dx) * m;
    float w11 = dy * dx * m;
    if (!(vy0 && vx0)) w00 = 0.f;
    if (!(vy0 && vx1)) w01 = 0.f;
    if (!(vy1 && vx0)) w10 = 0.f;
    if (!(vy1 && vx1)) w11 = 0.f;

    const uint4* p00 = (const uint4*)(xb + (size_t)(yc0 * WW + xc0) * 16);
    const uint4* p01 = (const uint4*)(xb + (size_t)(yc0 * WW + xc1) * 16);
    const uint4* p10 = (const uint4*)(xb + (size_t)(yc1 * WW + xc0) * 16);
    const uint4* p11 = (const uint4*)(xb + (size_t)(yc1 * WW + xc1) * 16);
    uint4 a0 = p00[0], a1 = p00[1];
    uint4 b0 = p01[0], b1 = p01[1];
    uint4 c0 = p10[0], c1 = p10[1];
    uint4 d0 = p11[0], d1 = p11[1];
    unsigned wA[8] = {a0.x, a0.y, a0.z, a0.w, a1.x, a1.y, a1.z, a1.w};
    unsigned wB[8] = {b0.x, b0.y, b0.z, b0.w, b1.x, b1.y, b1.z, b1.w};
    unsigned wC[8] = {c0.x, c0.y, c0.z, c0.w, c1.x, c1.y, c1.z, c1.w};
    unsigned wD[8] = {d0.x, d0.y, d0.z, d0.w, d1.x, d1.y, d1.z, d1.w};

    float s[16];
#pragma unroll
    for (int j = 0; j < 8; ++j) {
      s[2 * j]     = bf_lo(wA[j]) * w00 + bf_lo(wB[j]) * w01 + bf_lo(wC[j]) * w10 + bf_lo(wD[j]) * w11;
      s[2 * j + 1] = bf_hi(wA[j]) * w00 + bf_hi(wB[j]) * w01 + bf_hi(wC[j]) * w10 + bf_hi(wD[j]) * w11;
    }
    const float* wk = wt + (size_t)k * 256;
#pragma unroll
    for (int c = 0; c < 16; ++c)
#pragma unroll
      for (int o = 0; o < 16; ++o)
        acc[o] = fmaf(s[c], wk[c * 16 + o], acc[o]);
  }
  unsigned r[8];
#pragma unroll
  for (int j = 0; j < 8; ++j) {
    unsigned short lo = f2bf(fmaxf(acc[2 * j], 0.f));
    unsigned short hi = f2bf(fmaxf(acc[2 * j + 1], 0.f));
    r[j] = (unsigned)lo | ((unsigned)hi << 16);
  }
  uint4* d4 = (uint4*)(out + ((size_t)b * HWW + pixel) * 16);
  d4[0] = make_uint4(r[0], r[1], r[2], r[3]);
  d4[1] = make_uint4(r[4], r[5], r[6], r[7]);
}

extern "C" void kernel_launch(void* const* d_in, const int* in_sizes, int n_in,
                              void* d_out, int out_size, void* d_ws, size_t ws_size,
                              hipStream_t stream) {
  (void)in_sizes; (void)n_in; (void)out_size; (void)ws_size;
  const float* f_E = (const float*)d_in[0];
  const float* f_F = (const float*)d_in[1];
  const float* att_w1 = (const float*)d_in[2];
  const float* att_b1 = (const float*)d_in[3];
  const float* att_w2 = (const float*)d_in[4];
  const float* att_b2 = (const float*)d_in[5];
  const float* ref_w = (const float*)d_in[6];
  const float* ref_b = (const float*)d_in[7];
  const float* om_w1 = (const float*)d_in[8];
  const float* om_b1 = (const float*)d_in[9];
  const float* om_w2 = (const float*)d_in[10];
  const float* om_b2 = (const float*)d_in[11];
  const float* om_w3 = (const float*)d_in[12];
  const float* om_b3 = (const float*)d_in[13];
  const float* dcb_w = (const float*)d_in[14];
  const float* dcb_b = (const float*)d_in[15];
  const float* dcbref_w = (const float*)d_in[16];
  const float* dcbref_b = (const float*)d_in[17];
  const float* fin_w = (const float*)d_in[18];
  const float* fin_b = (const float*)d_in[19];
  float* outp = (float*)d_out;

  const size_t TN = (size_t)4 * HWW * 16;            // bf16 NHWC tensor elems
  unsigned short* XE  = (unsigned short*)d_ws;       // f_E  bf16 NHWC
  unsigned short* XF  = XE + TN;                     // f_F
  unsigned short* XA  = XF + TN;                     // conv_a; later om_t3
  unsigned short* XSA = XA + TN;                     // f_Esa; later f_Edc
  unsigned short* X2  = XSA + TN;                    // f_EFsa
  unsigned short* XT  = X2 + TN;                     // om_t2; later f_EFdc
  unsigned short* OMB = XT + TN;                     // om bf16 NCHW planes
  unsigned short* WM  = OMB + (size_t)4 * 27 * HWW;  // weight area

  unsigned short* WM_att1 = WM;                 // CIN32 OT1: 9*512 = 4608 ush
  unsigned short* WM_ref  = WM_att1 + 4608;
  unsigned short* WM_om1  = WM_ref + 4608;
  unsigned short* WM_om2  = WM_om1 + 4608;      // CIN16 OT1: 5*512 = 2560
  unsigned short* WM_om3  = WM_om2 + 2560;      // CIN16 OT2: 5120
  unsigned short* WM_dref = WM_om3 + 5120;
  unsigned short* WM_fin  = WM_dref + 4608;
  float* WF_att2 = (float*)(WM_fin + 4608);     // mode0: 144 f
  float* WF_dcb  = WF_att2 + 144;               // mode1: 2304 f

  RA ra;
  ra.d[0] = {att_w1, WM_att1, 32, 16, 2};
  ra.d[1] = {ref_w, WM_ref, 32, 16, 2};
  ra.d[2] = {om_w1, WM_om1, 32, 16, 2};
  ra.d[3] = {om_w2, WM_om2, 16, 16, 2};
  ra.d[4] = {om_w3, WM_om3, 16, 27, 2};
  ra.d[5] = {dcbref_w, WM_dref, 32, 16, 2};
  ra.d[6] = {fin_w, WM_fin, 32, 16, 2};
  ra.d[7] = {att_w2, WF_att2, 16, 1, 0};
  ra.d[8] = {dcb_w, WF_dcb, 16, 16, 1};
  repack_k<<<dim3(9), dim3(256), 0, stream>>>(ra);
  nhwc2_k<<<dim3(HWW / 256, 1, 4), dim3(256), 0, stream>>>(f_E, f_F, XE, XF);

  dim3 blk(256);
  dim3 gm(WW / 64, HH / 8, 4);   // 4 x 32 x 4 = 512 blocks

  // K1: conv_a = relu(conv(cat(f_E,f_F), att_w1))
  conv_nhwc<4, 1, 2, 16><<<gm, blk, 0, stream>>>(XE, XF, WM_att1, att_b1, XA);
  // K2: f_Esa = f_E * sigmoid(conv(conv_a, att_w2))
  gate_k<<<dim3(HH, 1, 4), blk, 0, stream>>>(XA, XE, WF_att2, att_b2, XSA);
  // K3: f_EFsa = relu(conv(cat(f_Esa,f_F), ref_w))
  conv_nhwc<4, 1, 2, 16><<<gm, blk, 0, stream>>>(XSA, XF, WM_ref, ref_b, X2);
  // K4: om_t2 = relu(conv(cat(f_E,f_F), om_w1))
  conv_nhwc<4, 1, 2, 16><<<gm, blk, 0, stream>>>(XE, XF, WM_om1, om_b1, XT);
  // K5: om_t3 = relu(conv(om_t2, om_w2))   (XA reused)
  conv_nhwc<2, 1, 2, 16><<<gm, blk, 0, stream>>>(XT, nullptr, WM_om2, om_b2, XA);
  // K6: om = conv(om_t3, om_w3)  raw, bf16 NCHW planes
  conv_nhwc<2, 2, 1, 27><<<gm, blk, 0, stream>>>(XA, nullptr, WM_om3, om_b3, OMB);
  // K7: f_Edc = relu(deform_conv(f_E, om, dcb_w))   (XSA reused)
  deform_v4<<<dim3(1024), blk, 0, stream>>>(XE, OMB, WF_dcb, dcb_b, XSA);
  // K8: f_EFdc = relu(conv(cat(f_Edc,f_F), dcbref_w))   (XT reused)
  conv_nhwc<4, 1, 2, 16><<<gm, blk, 0, stream>>>(XSA, XF, WM_dref, dcbref_b, XT);
  // K9: out = relu(conv(cat(f_EFsa,f_EFdc), fin_w))  -> fp32 NCHW
  conv_nhwc<4, 1, 0, 16><<<gm, blk, 0, stream>>>(X2, XT, WM_fin, fin_b, outp);
}